// Round 6
// baseline (169.568 us; speedup 1.0000x reference)
//
#include <hip/hip_runtime.h>

// Problem constants
#define N_TOTAL   65536   // B*H*W = 64*32*32
#define HW_SZ     1024    // H*W
#define CDIM      64      // embedding dim (= C)
#define K_CODES   1024
#define OUT_ELEMS 4194304 // 64*64*32*32
#define QT        256     // queries per kA block (32 per wave, rt=2, 8 waves)
#define QB        128     // queries per kB (epilogue) block
#define NCHUNK    4       // 4 chunks of 256 codes (64 KB each), double-buffered
#define TAU       0.004f  // rescue margin (> 2x analytic bf16x3 error bound ~1.5e-3)

// ws layout (bytes):
//   0       : enorm[1024]   f32
//   4096    : hist[1024]    u32
//   8192    : partials[512] f32
//   12288   : btab (256 KB) bf16 hi/lo table in MFMA B-FRAGMENT order
//   274432  : rd1g[65536] f32 (256 KB)  per-query best distance (bf16x3)
//   536576  : rd2g[65536] f32 (256 KB)  per-query runner-up distance
//   798720  : rig [65536] i32 (256 KB)  per-query argmin index
//   1060864 : xng [65536] f32 (256 KB)  per-query ||x||^2   (ends 1323008)

typedef __attribute__((ext_vector_type(8))) short short8;
typedef __attribute__((ext_vector_type(4))) float f32x4;

__device__ __forceinline__ unsigned short f2bf(float x) {
    unsigned u = __float_as_uint(x);
    return (unsigned short)((u + 0x7FFFu + ((u >> 16) & 1u)) >> 16);   // RNE
}
__device__ __forceinline__ float bf2f(unsigned short h) {
    return __uint_as_float(((unsigned)h) << 16);
}
__device__ __forceinline__ void gload_lds16(const void* g, void* l) {
    __builtin_amdgcn_global_load_lds(
        (const __attribute__((address_space(1))) void*)g,
        (__attribute__((address_space(3))) void*)l, 16, 0, 0);
}

// ---------------------------------------------------------------- k_prep ----
// Writes ||e||^2 and the frag-ordered bf16 hi/lo table.
__global__ void k_prep(const float* __restrict__ emb, float* __restrict__ enorm,
                       short* __restrict__ btab, unsigned int* __restrict__ hist) {
    int gid = blockIdx.x * 256 + threadIdx.x;        // 0..16383
    int r  = gid >> 4;           // code 0..1023
    int d0 = (gid & 15) * 4;     // dim base 0..60
    float4 v = *(const float4*)(emb + gid * 4);
    float s = v.x * v.x + v.y * v.y + v.z * v.z + v.w * v.w;
#pragma unroll
    for (int off = 1; off < 16; off <<= 1) s += __shfl_xor(s, off, 64);
    if ((gid & 15) == 0) enorm[r] = s;

    float vv[4] = {v.x, v.y, v.z, v.w};
    short h[4], l[4];
#pragma unroll
    for (int j = 0; j < 4; ++j) {
        unsigned short hh = f2bf(vv[j]);
        h[j] = (short)hh;
        l[j] = (short)f2bf(vv[j] - bf2f(hh));
    }
    int base = (r >> 4) * 2048 + (d0 >> 5) * 1024
             + ((((d0 >> 3) & 3) * 16 + (r & 15)) * 8) + (d0 & 7);
    *(short4*)&btab[base]       = make_short4(h[0], h[1], h[2], h[3]);
    *(short4*)&btab[base + 512] = make_short4(l[0], l[1], l[2], l[3]);

    if (gid < K_CODES) hist[gid] = 0u;
}

// -------------------------------------------------------------- k_argmin ----
// kA (diagnostic split): A-build + K-loop + col-reduce ONLY. Core identical to
// round 5 (512 thr = 8 waves, LDS-resident double-buffered chunks, explicit
// 2-stage register pipeline, bf16x3, top-2 tracking). Writes per-query
// {d1, d2, idx, ||x||^2} to ws; NO rescue/hist/out here.
__global__ __launch_bounds__(512, 2)
void k_argmin(const float* __restrict__ x, const short* __restrict__ btab,
              const float* __restrict__ enorm,
              float* __restrict__ rd1g, float* __restrict__ rd2g,
              int* __restrict__ rig, float* __restrict__ xng) {
    __shared__ __align__(16) short bufs[2][16 * 2048];   // 2 x 64 KB chunk buffers
    __shared__ __align__(16) float ens[K_CODES];         // 4 KB exact fp32 ||e||^2
    __shared__ float xnorm[QT];
    __shared__ float rd1[QT];
    __shared__ float rd2[QT];
    __shared__ int   ri[QT];

    const int tid  = threadIdx.x;
    const int lane = tid & 63;
    const int w    = tid >> 6;       // 0..7
    const int quad = lane >> 4;
    const int col  = lane & 15;

    const int n0  = blockIdx.x * QT;
    const int b   = n0 >> 10;
    const int hw0 = n0 & 1023;        // 256-aligned

    auto stage_async = [&](int c, int bsel) {
        const short* src = btab + c * (16 * 2048);
#pragma unroll
        for (int i = 0; i < 8; ++i) {
            int idx = i * 512 + tid;                  // 16B units, 0..4095
            gload_lds16(&src[idx * 8], (void*)&bufs[bsel][idx * 8]);
        }
    };

    stage_async(0, 0);
    if (tid < 256) gload_lds16(&enorm[tid * 4], (void*)&ens[tid * 4]);

    // A fragments straight from global; hi/lo bf16 split in regs; ||x||^2 via shfl.
    const float* xb = x + b * (CDIM * HW_SZ) + hw0 + col;
    short8 afr[2][2][2];     // [rt][kc][hi/lo]
#pragma unroll
    for (int rt = 0; rt < 2; ++rt) {
        float nloc = 0.f;
#pragma unroll
        for (int kc = 0; kc < 2; ++kc) {
#pragma unroll
            for (int j = 0; j < 8; ++j) {
                int c0 = (kc * 4 + quad) * 8 + j;
                float v = xb[c0 * HW_SZ + w * 32 + rt * 16];
                unsigned short hh = f2bf(v);
                afr[rt][kc][0][j] = (short)hh;
                afr[rt][kc][1][j] = (short)f2bf(v - bf2f(hh));
                nloc = __builtin_fmaf(v, v, nloc);
            }
        }
        nloc += __shfl_xor(nloc, 16, 64);
        nloc += __shfl_xor(nloc, 32, 64);
        if (quad == 0) xnorm[w * 32 + rt * 16 + col] = nloc;
    }

    float d1[8], d2[8];
    int   i1[8];
#pragma unroll
    for (int t = 0; t < 8; ++t) { d1[t] = 3.4e38f; d2[t] = 3.4e38f; i1[t] = 0; }

    __syncthreads();   // chunk 0 + ens + xnorm ready

    for (int c = 0; c < NCHUNK; ++c) {
        if (c + 1 < NCHUNK) stage_async(c + 1, (c + 1) & 1);
        const short* bs = &bufs[c & 1][0];
        const int cbase = c * 256;

        short8 Ba[4], Bb[4];          // [kc0hi, kc0lo, kc1hi, kc1lo]
        float  ena, enb;
        auto LDB = [&](short8 (&B)[4], float& en, int ctl) {
            const short* fp = bs + ctl * 2048 + lane * 8;
            B[0] = *(const short8*)(fp);
            B[1] = *(const short8*)(fp + 512);
            B[2] = *(const short8*)(fp + 1024);
            B[3] = *(const short8*)(fp + 1536);
            en   = ens[cbase + ctl * 16 + col];
        };
        auto COMP = [&](const short8 (&B)[4], float en, int mycode) {
#pragma unroll
            for (int rt = 0; rt < 2; ++rt) {
                f32x4 a0 = {0.f, 0.f, 0.f, 0.f};
                f32x4 a1 = {0.f, 0.f, 0.f, 0.f};
                a0 = __builtin_amdgcn_mfma_f32_16x16x32_bf16(afr[rt][0][1], B[0], a0, 0, 0, 0);
                a1 = __builtin_amdgcn_mfma_f32_16x16x32_bf16(afr[rt][1][1], B[2], a1, 0, 0, 0);
                a0 = __builtin_amdgcn_mfma_f32_16x16x32_bf16(afr[rt][0][0], B[1], a0, 0, 0, 0);
                a1 = __builtin_amdgcn_mfma_f32_16x16x32_bf16(afr[rt][1][0], B[3], a1, 0, 0, 0);
                a0 = __builtin_amdgcn_mfma_f32_16x16x32_bf16(afr[rt][0][0], B[0], a0, 0, 0, 0);
                a1 = __builtin_amdgcn_mfma_f32_16x16x32_bf16(afr[rt][1][0], B[2], a1, 0, 0, 0);
#pragma unroll
                for (int reg = 0; reg < 4; ++reg) {
                    int t = rt * 4 + reg;
                    float dot = a0[reg] + a1[reg];
                    float d   = __builtin_fmaf(dot, -2.f, en);
                    float d1o = d1[t];
                    d2[t] = __builtin_amdgcn_fmed3f(d, d1o, d2[t]);
                    d1[t] = fminf(d, d1o);
                    i1[t] = (d < d1o) ? mycode : i1[t];
                }
            }
        };

        LDB(Ba, ena, 0);
#pragma unroll
        for (int ctl = 0; ctl < 16; ctl += 2) {
            LDB(Bb, enb, ctl + 1);
            COMP(Ba, ena, cbase + ctl * 16 + col);
            if (ctl + 2 < 16) LDB(Ba, ena, ctl + 2);
            COMP(Bb, enb, cbase + (ctl + 1) * 16 + col);
        }
        __syncthreads();
    }

    // reduce across 16 cols per query row (codes ascend with col: lex-min ok)
#pragma unroll
    for (int t = 0; t < 8; ++t) {
        float a1 = d1[t], a2 = d2[t];
        int ai = i1[t];
#pragma unroll
        for (int off = 1; off < 16; off <<= 1) {
            float o1 = __shfl_xor(a1, off, 64);
            float o2 = __shfl_xor(a2, off, 64);
            int   oi = __shfl_xor(ai, off, 64);
            if (o1 < a1 || (o1 == a1 && oi < ai)) {
                float loser = a1; a2 = fminf(fminf(a2, o2), loser); a1 = o1; ai = oi;
            } else {
                a2 = fminf(fminf(a2, o2), o1);
            }
        }
        d1[t] = a1; d2[t] = a2; i1[t] = ai;
    }

    if (col == 0) {
#pragma unroll
        for (int rt = 0; rt < 2; ++rt)
#pragma unroll
            for (int reg = 0; reg < 4; ++reg) {
                int t = rt * 4 + reg;
                int m = w * 32 + rt * 16 + quad * 4 + reg;
                rd1[m] = d1[t];
                rd2[m] = d2[t];
                ri [m] = i1[t];
            }
    }
    __syncthreads();

    // coalesced copy-out of per-query results
    if (tid < QT) {
        rd1g[n0 + tid] = rd1[tid];
        rd2g[n0 + tid] = rd2[tid];
        rig [n0 + tid] = ri[tid];
        xng [n0 + tid] = xnorm[tid];
    }
}

// ----------------------------------------------------------------- k_epi ----
// kB (diagnostic split): TAU-margin exact fp32 rescue, hist atomics, SSE
// partials, and output write (exact fp32 emb gather -> LDS transpose ->
// coalesced store). 256 thr, ~26 KB LDS -> high occupancy.
__global__ __launch_bounds__(256, 4)
void k_epi(const float* __restrict__ x, const float* __restrict__ emb,
           const float* __restrict__ enorm,
           const float* __restrict__ rd1g, const float* __restrict__ rd2g,
           const int* __restrict__ rig, const float* __restrict__ xng,
           unsigned int* __restrict__ hist, float* __restrict__ partials,
           float* __restrict__ out) {
    __shared__ __align__(16) float ens[K_CODES];     // 4 KB exact fp32 ||e||^2
    __shared__ float rd1[QB];
    __shared__ float rd2[QB];
    __shared__ int   ri[QB];
    __shared__ float xn[QB];
    __shared__ int   flist[QB];
    __shared__ __align__(16) float xqf[CDIM];
    __shared__ float wdd[4];
    __shared__ int   wii[4];
    __shared__ float spw[2];
    __shared__ int   nflag;
    __shared__ __align__(16) float tile[64 * 72];    // 18.4 KB transpose tile

    const int tid  = threadIdx.x;
    const int lane = tid & 63;
    const int w    = tid >> 6;       // 0..3

    const int n0  = blockIdx.x * QB;
    const int b   = n0 >> 10;
    const int hw0 = n0 & 1023;        // 128-aligned

    gload_lds16(&enorm[tid * 4], (void*)&ens[tid * 4]);
    if (tid == 0) nflag = 0;
    if (tid < QB) {
        rd1[tid] = rd1g[n0 + tid];
        rd2[tid] = rd2g[n0 + tid];
        ri [tid] = rig [n0 + tid];
        xn [tid] = xng [n0 + tid];
    }
    __syncthreads();   // ens + loads landed

    if (tid < QB) {
        if (rd2[tid] - rd1[tid] < TAU) {
            int slot = atomicAdd(&nflag, 1);
            flist[slot] = tid;
        }
    }
    __syncthreads();

    // ---- exact fp32 rescue (avg nflag ~0-1 per block) ----
    for (int f = 0; f < nflag; ++f) {
        const int q = flist[f];
        if (tid < CDIM) xqf[tid] = x[b * (CDIM * HW_SZ) + tid * HW_SZ + hw0 + q];
        __syncthreads();
        float dm = 3.4e38f; int im = 0;
#pragma unroll
        for (int cd = 0; cd < 4; ++cd) {
            const int k = tid + cd * 256;            // codes ascend with cd
            const float4* er = (const float4*)(emb + k * CDIM);
            const float4* xr = (const float4*)xqf;
            float dot = 0.f;
#pragma unroll
            for (int c4 = 0; c4 < 16; ++c4) {
                float4 e = er[c4], xv = xr[c4];
                dot += e.x * xv.x + e.y * xv.y + e.z * xv.z + e.w * xv.w;
            }
            float d = ens[k] - 2.f * dot;            // exact fp32
            if (d < dm) { dm = d; im = k; }
        }
#pragma unroll
        for (int off = 1; off < 64; off <<= 1) {
            float od = __shfl_xor(dm, off, 64);
            int   oi = __shfl_xor(im, off, 64);
            if (od < dm || (od == dm && oi < im)) { dm = od; im = oi; }
        }
        if (lane == 0) { wdd[w] = dm; wii[w] = im; }
        __syncthreads();
        if (tid == 0) {
            float bd = wdd[0]; int bi = wii[0];
#pragma unroll
            for (int ww = 1; ww < 4; ++ww)
                if (wdd[ww] < bd || (wdd[ww] == bd && wii[ww] < bi)) { bd = wdd[ww]; bi = wii[ww]; }
            rd1[q] = bd; ri[q] = bi;                 // final exact result
        }
        __syncthreads();
    }

    // ---- hist + SSE partial on FINAL indices ----
    if (tid < QB) {
        int ai = ri[tid];
        atomicAdd(&hist[ai], 1u);
        float sp = rd1[tid] + xn[tid];               // ||q-x||^2 (exact for rescued)
#pragma unroll
        for (int off = 32; off; off >>= 1) sp += __shfl_down(sp, off, 64);
        if (lane == 0) spw[w] = sp;
    }
    __syncthreads();
    if (tid == 0) partials[blockIdx.x] = spw[0] + spw[1];

    // ---- output write: two 64-query halves; EXACT fp32 emb gather ----
#pragma unroll
    for (int h = 0; h < 2; ++h) {
        {   // gather: thread = (q = tid>>2, j = tid&3) -> 16 dims from emb row
            int q = tid >> 2, j = tid & 3;
            int code = ri[h * 64 + q];
            const float4* er = (const float4*)(emb + code * CDIM + j * 16);
            float4 e0 = er[0], e1 = er[1], e2 = er[2], e3 = er[3];
            float* dst = &tile[q * 72 + j * 16];
            *(float4*)&dst[0]  = e0;
            *(float4*)&dst[4]  = e1;
            *(float4*)&dst[8]  = e2;
            *(float4*)&dst[12] = e3;
        }
        __syncthreads();
        {   // transposed coalesced write
            int c = tid >> 2;
            float* ob = out + b * (CDIM * HW_SZ) + c * HW_SZ + hw0 + h * 64;
#pragma unroll
            for (int p = 0; p < 4; ++p) {
                int q = ((tid & 3) + p * 4) * 4;   // 0..60
                float4 v;
                v.x = tile[(q + 0) * 72 + c];
                v.y = tile[(q + 1) * 72 + c];
                v.z = tile[(q + 2) * 72 + c];
                v.w = tile[(q + 3) * 72 + c];
                *(float4*)&ob[q] = v;
            }
        }
        if (h == 0) __syncthreads();
    }
}

// --------------------------------------------------------------- k_final ----
// 1 block; reads partials (512) + hist (1024) from previous dispatches.
__global__ void k_final(const float* __restrict__ partials,
                        const unsigned int* __restrict__ hist,
                        float* __restrict__ out) {
    int tid = threadIdx.x;   // 256
    float ss = partials[tid] + partials[256 + tid];
    float s = 0.f;
#pragma unroll
    for (int i = 0; i < 4; ++i) {
        float p = (float)hist[i * 256 + tid] * (1.0f / 65536.0f);
        s += p * logf(p + 1e-10f);
    }
    __shared__ float fin[8];
#pragma unroll
    for (int off = 32; off; off >>= 1) {
        ss += __shfl_down(ss, off, 64);
        s  += __shfl_down(s, off, 64);
    }
    if ((tid & 63) == 0) { fin[tid >> 6] = ss; fin[4 + (tid >> 6)] = s; }
    __syncthreads();
    if (tid == 0) {
        float sse = fin[0] + fin[1] + fin[2] + fin[3];
        float ent = fin[4] + fin[5] + fin[6] + fin[7];
        out[OUT_ELEMS]     = 1.25f * sse * (1.0f / (float)OUT_ELEMS);  // loss
        out[OUT_ELEMS + 1] = expf(-ent);                                // perplexity
    }
}

// ---------------------------------------------------------------- launch ----
extern "C" void kernel_launch(void* const* d_in, const int* in_sizes, int n_in,
                              void* d_out, int out_size, void* d_ws, size_t ws_size,
                              hipStream_t stream) {
    const float* x   = (const float*)d_in[0];
    const float* emb = (const float*)d_in[1];
    float* out = (float*)d_out;
    char* ws = (char*)d_ws;
    float*        enorm    = (float*)(ws);
    unsigned int* hist     = (unsigned int*)(ws + 4096);
    float*        partials = (float*)(ws + 8192);
    short*        btab     = (short*)(ws + 12288);
    float*        rd1g     = (float*)(ws + 274432);
    float*        rd2g     = (float*)(ws + 536576);
    int*          rig      = (int*)  (ws + 798720);
    float*        xng      = (float*)(ws + 1060864);

    k_prep  <<<64, 256, 0, stream>>>(emb, enorm, btab, hist);
    k_argmin<<<N_TOTAL / QT, 512, 0, stream>>>(x, btab, enorm, rd1g, rd2g, rig, xng);
    k_epi   <<<N_TOTAL / QB, 256, 0, stream>>>(x, emb, enorm, rd1g, rd2g, rig, xng,
                                               hist, partials, out);
    k_final <<<1, 256, 0, stream>>>(partials, hist, out);
}

// Round 7
// 154.393 us; speedup vs baseline: 1.0983x; 1.0983x over previous
//
#include <hip/hip_runtime.h>

// Problem constants
#define N_TOTAL   65536   // B*H*W = 64*32*32
#define HW_SZ     1024    // H*W
#define CDIM      64      // embedding dim (= C)
#define K_CODES   1024
#define OUT_ELEMS 4194304 // 64*64*32*32
#define QT        256     // queries per kA block (32 per wave, rt=2, 8 waves)
#define QB        128     // queries per kB (epilogue) block
#define NCHUNK    4       // 4 chunks of 256 codes (64 KB each), double-buffered
#define TAU       0.004f  // rescue margin (> 2x analytic bf16x3 error bound ~1.5e-3)

// ws layout (bytes):
//   0       : enorm[1024]   f32
//   4096    : (unused)
//   8192    : partials[512] f32
//   12288   : btab (256 KB) bf16 hi/lo table in MFMA B-FRAGMENT order
//   274432  : rd1g[65536] f32 (256 KB)  per-query best distance (bf16x3)
//   536576  : rd2g[65536] f32 (256 KB)  per-query runner-up distance
//   798720  : rig [65536] i32 (256 KB)  per-query argmin index (FINAL after k_epi)
//   1060864 : xng [65536] f32 (256 KB)  per-query ||x||^2   (ends 1323008)

typedef __attribute__((ext_vector_type(8))) short short8;
typedef __attribute__((ext_vector_type(4))) float f32x4;

__device__ __forceinline__ unsigned short f2bf(float x) {
    unsigned u = __float_as_uint(x);
    return (unsigned short)((u + 0x7FFFu + ((u >> 16) & 1u)) >> 16);   // RNE
}
__device__ __forceinline__ float bf2f(unsigned short h) {
    return __uint_as_float(((unsigned)h) << 16);
}
__device__ __forceinline__ void gload_lds16(const void* g, void* l) {
    __builtin_amdgcn_global_load_lds(
        (const __attribute__((address_space(1))) void*)g,
        (__attribute__((address_space(3))) void*)l, 16, 0, 0);
}

// ---------------------------------------------------------------- k_prep ----
// Writes ||e||^2 and the frag-ordered bf16 hi/lo table.
__global__ void k_prep(const float* __restrict__ emb, float* __restrict__ enorm,
                       short* __restrict__ btab) {
    int gid = blockIdx.x * 256 + threadIdx.x;        // 0..16383
    int r  = gid >> 4;           // code 0..1023
    int d0 = (gid & 15) * 4;     // dim base 0..60
    float4 v = *(const float4*)(emb + gid * 4);
    float s = v.x * v.x + v.y * v.y + v.z * v.z + v.w * v.w;
#pragma unroll
    for (int off = 1; off < 16; off <<= 1) s += __shfl_xor(s, off, 64);
    if ((gid & 15) == 0) enorm[r] = s;

    float vv[4] = {v.x, v.y, v.z, v.w};
    short h[4], l[4];
#pragma unroll
    for (int j = 0; j < 4; ++j) {
        unsigned short hh = f2bf(vv[j]);
        h[j] = (short)hh;
        l[j] = (short)f2bf(vv[j] - bf2f(hh));
    }
    int base = (r >> 4) * 2048 + (d0 >> 5) * 1024
             + ((((d0 >> 3) & 3) * 16 + (r & 15)) * 8) + (d0 & 7);
    *(short4*)&btab[base]       = make_short4(h[0], h[1], h[2], h[3]);
    *(short4*)&btab[base + 512] = make_short4(l[0], l[1], l[2], l[3]);
}

// -------------------------------------------------------------- k_argmin ----
// kA: A-build + K-loop + col-reduce ONLY (identical core to rounds 5/6).
// Writes per-query {d1, d2, idx, ||x||^2} to ws.
__global__ __launch_bounds__(512, 2)
void k_argmin(const float* __restrict__ x, const short* __restrict__ btab,
              const float* __restrict__ enorm,
              float* __restrict__ rd1g, float* __restrict__ rd2g,
              int* __restrict__ rig, float* __restrict__ xng) {
    __shared__ __align__(16) short bufs[2][16 * 2048];   // 2 x 64 KB chunk buffers
    __shared__ __align__(16) float ens[K_CODES];         // 4 KB exact fp32 ||e||^2
    __shared__ float xnorm[QT];
    __shared__ float rd1[QT];
    __shared__ float rd2[QT];
    __shared__ int   ri[QT];

    const int tid  = threadIdx.x;
    const int lane = tid & 63;
    const int w    = tid >> 6;       // 0..7
    const int quad = lane >> 4;
    const int col  = lane & 15;

    const int n0  = blockIdx.x * QT;
    const int b   = n0 >> 10;
    const int hw0 = n0 & 1023;        // 256-aligned

    auto stage_async = [&](int c, int bsel) {
        const short* src = btab + c * (16 * 2048);
#pragma unroll
        for (int i = 0; i < 8; ++i) {
            int idx = i * 512 + tid;                  // 16B units, 0..4095
            gload_lds16(&src[idx * 8], (void*)&bufs[bsel][idx * 8]);
        }
    };

    stage_async(0, 0);
    if (tid < 256) gload_lds16(&enorm[tid * 4], (void*)&ens[tid * 4]);

    // A fragments straight from global; hi/lo bf16 split in regs; ||x||^2 via shfl.
    const float* xb = x + b * (CDIM * HW_SZ) + hw0 + col;
    short8 afr[2][2][2];     // [rt][kc][hi/lo]
#pragma unroll
    for (int rt = 0; rt < 2; ++rt) {
        float nloc = 0.f;
#pragma unroll
        for (int kc = 0; kc < 2; ++kc) {
#pragma unroll
            for (int j = 0; j < 8; ++j) {
                int c0 = (kc * 4 + quad) * 8 + j;
                float v = xb[c0 * HW_SZ + w * 32 + rt * 16];
                unsigned short hh = f2bf(v);
                afr[rt][kc][0][j] = (short)hh;
                afr[rt][kc][1][j] = (short)f2bf(v - bf2f(hh));
                nloc = __builtin_fmaf(v, v, nloc);
            }
        }
        nloc += __shfl_xor(nloc, 16, 64);
        nloc += __shfl_xor(nloc, 32, 64);
        if (quad == 0) xnorm[w * 32 + rt * 16 + col] = nloc;
    }

    float d1[8], d2[8];
    int   i1[8];
#pragma unroll
    for (int t = 0; t < 8; ++t) { d1[t] = 3.4e38f; d2[t] = 3.4e38f; i1[t] = 0; }

    __syncthreads();   // chunk 0 + ens + xnorm ready

    for (int c = 0; c < NCHUNK; ++c) {
        if (c + 1 < NCHUNK) stage_async(c + 1, (c + 1) & 1);
        const short* bs = &bufs[c & 1][0];
        const int cbase = c * 256;

        short8 Ba[4], Bb[4];          // [kc0hi, kc0lo, kc1hi, kc1lo]
        float  ena, enb;
        auto LDB = [&](short8 (&B)[4], float& en, int ctl) {
            const short* fp = bs + ctl * 2048 + lane * 8;
            B[0] = *(const short8*)(fp);
            B[1] = *(const short8*)(fp + 512);
            B[2] = *(const short8*)(fp + 1024);
            B[3] = *(const short8*)(fp + 1536);
            en   = ens[cbase + ctl * 16 + col];
        };
        auto COMP = [&](const short8 (&B)[4], float en, int mycode) {
#pragma unroll
            for (int rt = 0; rt < 2; ++rt) {
                f32x4 a0 = {0.f, 0.f, 0.f, 0.f};
                f32x4 a1 = {0.f, 0.f, 0.f, 0.f};
                a0 = __builtin_amdgcn_mfma_f32_16x16x32_bf16(afr[rt][0][1], B[0], a0, 0, 0, 0);
                a1 = __builtin_amdgcn_mfma_f32_16x16x32_bf16(afr[rt][1][1], B[2], a1, 0, 0, 0);
                a0 = __builtin_amdgcn_mfma_f32_16x16x32_bf16(afr[rt][0][0], B[1], a0, 0, 0, 0);
                a1 = __builtin_amdgcn_mfma_f32_16x16x32_bf16(afr[rt][1][0], B[3], a1, 0, 0, 0);
                a0 = __builtin_amdgcn_mfma_f32_16x16x32_bf16(afr[rt][0][0], B[0], a0, 0, 0, 0);
                a1 = __builtin_amdgcn_mfma_f32_16x16x32_bf16(afr[rt][1][0], B[2], a1, 0, 0, 0);
#pragma unroll
                for (int reg = 0; reg < 4; ++reg) {
                    int t = rt * 4 + reg;
                    float dot = a0[reg] + a1[reg];
                    float d   = __builtin_fmaf(dot, -2.f, en);
                    float d1o = d1[t];
                    d2[t] = __builtin_amdgcn_fmed3f(d, d1o, d2[t]);
                    d1[t] = fminf(d, d1o);
                    i1[t] = (d < d1o) ? mycode : i1[t];
                }
            }
        };

        LDB(Ba, ena, 0);
#pragma unroll
        for (int ctl = 0; ctl < 16; ctl += 2) {
            LDB(Bb, enb, ctl + 1);
            COMP(Ba, ena, cbase + ctl * 16 + col);
            if (ctl + 2 < 16) LDB(Ba, ena, ctl + 2);
            COMP(Bb, enb, cbase + (ctl + 1) * 16 + col);
        }
        __syncthreads();
    }

    // reduce across 16 cols per query row (codes ascend with col: lex-min ok)
#pragma unroll
    for (int t = 0; t < 8; ++t) {
        float a1 = d1[t], a2 = d2[t];
        int ai = i1[t];
#pragma unroll
        for (int off = 1; off < 16; off <<= 1) {
            float o1 = __shfl_xor(a1, off, 64);
            float o2 = __shfl_xor(a2, off, 64);
            int   oi = __shfl_xor(ai, off, 64);
            if (o1 < a1 || (o1 == a1 && oi < ai)) {
                float loser = a1; a2 = fminf(fminf(a2, o2), loser); a1 = o1; ai = oi;
            } else {
                a2 = fminf(fminf(a2, o2), o1);
            }
        }
        d1[t] = a1; d2[t] = a2; i1[t] = ai;
    }

    if (col == 0) {
#pragma unroll
        for (int rt = 0; rt < 2; ++rt)
#pragma unroll
            for (int reg = 0; reg < 4; ++reg) {
                int t = rt * 4 + reg;
                int m = w * 32 + rt * 16 + quad * 4 + reg;
                rd1[m] = d1[t];
                rd2[m] = d2[t];
                ri [m] = i1[t];
            }
    }
    __syncthreads();

    // coalesced copy-out of per-query results
    if (tid < QT) {
        rd1g[n0 + tid] = rd1[tid];
        rd2g[n0 + tid] = rd2[tid];
        rig [n0 + tid] = ri[tid];
        xng [n0 + tid] = xnorm[tid];
    }
}

// ----------------------------------------------------------------- k_epi ----
// kB: TAU-margin exact fp32 rescue, SSE partials, FINAL-index writeback to
// rig (NO global hist atomics), output write (exact fp32 emb gather -> LDS
// transpose -> coalesced store). (256,2): 128-VGPR tier, no spills.
__global__ __launch_bounds__(256, 2)
void k_epi(const float* __restrict__ x, const float* __restrict__ emb,
           const float* __restrict__ enorm,
           const float* __restrict__ rd1g, const float* __restrict__ rd2g,
           int* __restrict__ rig, const float* __restrict__ xng,
           float* __restrict__ partials, float* __restrict__ out) {
    __shared__ __align__(16) float ens[K_CODES];     // 4 KB exact fp32 ||e||^2
    __shared__ float rd1[QB];
    __shared__ float rd2[QB];
    __shared__ int   ri[QB];
    __shared__ float xn[QB];
    __shared__ int   flist[QB];
    __shared__ __align__(16) float xqf[CDIM];
    __shared__ float wdd[4];
    __shared__ int   wii[4];
    __shared__ float spw[2];
    __shared__ int   nflag;
    __shared__ __align__(16) float tile[64 * 72];    // 18.4 KB transpose tile

    const int tid  = threadIdx.x;
    const int lane = tid & 63;
    const int w    = tid >> 6;       // 0..3

    const int n0  = blockIdx.x * QB;
    const int b   = n0 >> 10;
    const int hw0 = n0 & 1023;        // 128-aligned

    gload_lds16(&enorm[tid * 4], (void*)&ens[tid * 4]);
    if (tid == 0) nflag = 0;
    if (tid < QB) {
        rd1[tid] = rd1g[n0 + tid];
        rd2[tid] = rd2g[n0 + tid];
        ri [tid] = rig [n0 + tid];
        xn [tid] = xng [n0 + tid];
    }
    __syncthreads();   // ens + loads landed

    if (tid < QB) {
        if (rd2[tid] - rd1[tid] < TAU) {
            int slot = atomicAdd(&nflag, 1);
            flist[slot] = tid;
        }
    }
    __syncthreads();

    // ---- exact fp32 rescue (avg nflag ~0-1 per block) ----
    for (int f = 0; f < nflag; ++f) {
        const int q = flist[f];
        if (tid < CDIM) xqf[tid] = x[b * (CDIM * HW_SZ) + tid * HW_SZ + hw0 + q];
        __syncthreads();
        float dm = 3.4e38f; int im = 0;
        for (int cd = 0; cd < 4; ++cd) {
            const int k = tid + cd * 256;            // codes ascend with cd
            const float4* er = (const float4*)(emb + k * CDIM);
            const float4* xr = (const float4*)xqf;
            float dot = 0.f;
#pragma unroll 4
            for (int c4 = 0; c4 < 16; ++c4) {
                float4 e = er[c4], xv = xr[c4];
                dot += e.x * xv.x + e.y * xv.y + e.z * xv.z + e.w * xv.w;
            }
            float d = ens[k] - 2.f * dot;            // exact fp32
            if (d < dm) { dm = d; im = k; }
        }
#pragma unroll
        for (int off = 1; off < 64; off <<= 1) {
            float od = __shfl_xor(dm, off, 64);
            int   oi = __shfl_xor(im, off, 64);
            if (od < dm || (od == dm && oi < im)) { dm = od; im = oi; }
        }
        if (lane == 0) { wdd[w] = dm; wii[w] = im; }
        __syncthreads();
        if (tid == 0) {
            float bd = wdd[0]; int bi = wii[0];
#pragma unroll
            for (int ww = 1; ww < 4; ++ww)
                if (wdd[ww] < bd || (wdd[ww] == bd && wii[ww] < bi)) { bd = wdd[ww]; bi = wii[ww]; }
            rd1[q] = bd; ri[q] = bi;                 // final exact result
        }
        __syncthreads();
    }

    // ---- FINAL-index writeback + SSE partial (no global atomics) ----
    if (tid < QB) {
        rig[n0 + tid] = ri[tid];                     // final indices for k_final's hist
        float sp = rd1[tid] + xn[tid];               // ||q-x||^2 (exact for rescued)
#pragma unroll
        for (int off = 32; off; off >>= 1) sp += __shfl_down(sp, off, 64);
        if (lane == 0) spw[w] = sp;
    }
    __syncthreads();
    if (tid == 0) partials[blockIdx.x] = spw[0] + spw[1];

    // ---- output write: two 64-query halves; EXACT fp32 emb gather ----
#pragma unroll
    for (int h = 0; h < 2; ++h) {
        {   // gather: thread = (q = tid>>2, j = tid&3) -> 16 dims from emb row
            int q = tid >> 2, j = tid & 3;
            int code = ri[h * 64 + q];
            const float4* er = (const float4*)(emb + code * CDIM + j * 16);
            float4 e0 = er[0], e1 = er[1], e2 = er[2], e3 = er[3];
            float* dst = &tile[q * 72 + j * 16];
            *(float4*)&dst[0]  = e0;
            *(float4*)&dst[4]  = e1;
            *(float4*)&dst[8]  = e2;
            *(float4*)&dst[12] = e3;
        }
        __syncthreads();
        {   // transposed coalesced write
            int c = tid >> 2;
            float* ob = out + b * (CDIM * HW_SZ) + c * HW_SZ + hw0 + h * 64;
#pragma unroll
            for (int p = 0; p < 4; ++p) {
                int q = ((tid & 3) + p * 4) * 4;   // 0..60
                float4 v;
                v.x = tile[(q + 0) * 72 + c];
                v.y = tile[(q + 1) * 72 + c];
                v.z = tile[(q + 2) * 72 + c];
                v.w = tile[(q + 3) * 72 + c];
                *(float4*)&ob[q] = v;
            }
        }
        if (h == 0) __syncthreads();
    }
}

// --------------------------------------------------------------- k_final ----
// 1 block x 1024 thr. Builds the 1024-bin histogram from FINAL indices in
// LDS (no cross-XCD atomic contention), then entropy + loss.
__global__ __launch_bounds__(1024, 1)
void k_final(const int* __restrict__ rig, const float* __restrict__ partials,
             float* __restrict__ out) {
    __shared__ unsigned int lhist[K_CODES];
    __shared__ float fin[32];
    int tid = threadIdx.x;   // 0..1023

    if (tid < K_CODES) lhist[tid] = 0u;
    __syncthreads();
#pragma unroll
    for (int i = 0; i < N_TOTAL / 1024; ++i)     // 64 coalesced passes
        atomicAdd(&lhist[rig[i * 1024 + tid]], 1u);
    __syncthreads();

    float ss = (tid < 512) ? partials[tid] : 0.f;
    float p  = (float)lhist[tid] * (1.0f / 65536.0f);
    float s  = p * logf(p + 1e-10f);
#pragma unroll
    for (int off = 32; off; off >>= 1) {
        ss += __shfl_down(ss, off, 64);
        s  += __shfl_down(s, off, 64);
    }
    if ((tid & 63) == 0) { fin[tid >> 6] = ss; fin[16 + (tid >> 6)] = s; }
    __syncthreads();
    if (tid == 0) {
        float sse = 0.f, ent = 0.f;
#pragma unroll
        for (int i = 0; i < 16; ++i) { sse += fin[i]; ent += fin[16 + i]; }
        out[OUT_ELEMS]     = 1.25f * sse * (1.0f / (float)OUT_ELEMS);  // loss
        out[OUT_ELEMS + 1] = expf(-ent);                                // perplexity
    }
}

// ---------------------------------------------------------------- launch ----
extern "C" void kernel_launch(void* const* d_in, const int* in_sizes, int n_in,
                              void* d_out, int out_size, void* d_ws, size_t ws_size,
                              hipStream_t stream) {
    const float* x   = (const float*)d_in[0];
    const float* emb = (const float*)d_in[1];
    float* out = (float*)d_out;
    char* ws = (char*)d_ws;
    float*        enorm    = (float*)(ws);
    float*        partials = (float*)(ws + 8192);
    short*        btab     = (short*)(ws + 12288);
    float*        rd1g     = (float*)(ws + 274432);
    float*        rd2g     = (float*)(ws + 536576);
    int*          rig      = (int*)  (ws + 798720);
    float*        xng      = (float*)(ws + 1060864);

    k_prep  <<<64, 256, 0, stream>>>(emb, enorm, btab);
    k_argmin<<<N_TOTAL / QT, 512, 0, stream>>>(x, btab, enorm, rd1g, rd2g, rig, xng);
    k_epi   <<<N_TOTAL / QB, 256, 0, stream>>>(x, emb, enorm, rd1g, rd2g, rig, xng,
                                               partials, out);
    k_final <<<1, 1024, 0, stream>>>(rig, partials, out);
}

// Round 8
// 154.050 us; speedup vs baseline: 1.1007x; 1.0022x over previous
//
#include <hip/hip_runtime.h>

// Problem constants
#define N_TOTAL   65536   // B*H*W = 64*32*32
#define HW_SZ     1024    // H*W
#define CDIM      64      // embedding dim (= C)
#define K_CODES   1024
#define OUT_ELEMS 4194304 // 64*64*32*32
#define QT        256     // queries per block (32 per wave, rt=2, 8 waves)
#define NCHUNK    4       // 4 chunks of 256 codes (64 KB each), double-buffered
#define TAU       0.004f  // rescue margin (> 2x analytic bf16x3 error bound ~1.5e-3)

// ws layout (bytes):
//   0       : enorm[1024]   f32
//   8192    : partials[256] f32
//   12288   : btab (256 KB) bf16 hi/lo table in MFMA B-FRAGMENT order:
//             short index = ct*2048 + kc*1024 + h*512 + lane*8 + j
//             code = ct*16 + (lane&15), dim = (kc*4 + (lane>>4))*8 + j
//   274432  : rig[65536] i32 (256 KB) FINAL per-query argmin index

typedef __attribute__((ext_vector_type(8))) short short8;
typedef __attribute__((ext_vector_type(4))) float f32x4;

__device__ __forceinline__ unsigned short f2bf(float x) {
    unsigned u = __float_as_uint(x);
    return (unsigned short)((u + 0x7FFFu + ((u >> 16) & 1u)) >> 16);   // RNE
}
__device__ __forceinline__ float bf2f(unsigned short h) {
    return __uint_as_float(((unsigned)h) << 16);
}
__device__ __forceinline__ void gload_lds16(const void* g, void* l) {
    __builtin_amdgcn_global_load_lds(
        (const __attribute__((address_space(1))) void*)g,
        (__attribute__((address_space(3))) void*)l, 16, 0, 0);
}

// ---------------------------------------------------------------- k_prep ----
// Writes ||e||^2 and the frag-ordered bf16 hi/lo table.
__global__ void k_prep(const float* __restrict__ emb, float* __restrict__ enorm,
                       short* __restrict__ btab) {
    int gid = blockIdx.x * 256 + threadIdx.x;        // 0..16383
    int r  = gid >> 4;           // code 0..1023
    int d0 = (gid & 15) * 4;     // dim base 0..60
    float4 v = *(const float4*)(emb + gid * 4);
    float s = v.x * v.x + v.y * v.y + v.z * v.z + v.w * v.w;
#pragma unroll
    for (int off = 1; off < 16; off <<= 1) s += __shfl_xor(s, off, 64);
    if ((gid & 15) == 0) enorm[r] = s;

    float vv[4] = {v.x, v.y, v.z, v.w};
    short h[4], l[4];
#pragma unroll
    for (int j = 0; j < 4; ++j) {
        unsigned short hh = f2bf(vv[j]);
        h[j] = (short)hh;
        l[j] = (short)f2bf(vv[j] - bf2f(hh));
    }
    int base = (r >> 4) * 2048 + (d0 >> 5) * 1024
             + ((((d0 >> 3) & 3) * 16 + (r & 15)) * 8) + (d0 & 7);
    *(short4*)&btab[base]       = make_short4(h[0], h[1], h[2], h[3]);
    *(short4*)&btab[base + 512] = make_short4(l[0], l[1], l[2], l[3]);
}

// -------------------------------------------------------------- k_argmin ----
// FUSED: K-loop core identical to round 5 + spill-free atomic-free epilogue.
// 512 thr = 8 waves; QT=256 queries/block; grid 256 = 1 block/CU.
// Epilogue: TAU-margin exact fp32 rescue, SSE partial, FINAL-index write to
// rig (k_final builds LDS hist), out-write via fp32 emb gather + LDS transpose
// (tile aliases the chunk buffers).
__global__ __launch_bounds__(512, 2)
void k_argmin(const float* __restrict__ x, const float* __restrict__ emb,
              const short* __restrict__ btab, const float* __restrict__ enorm,
              int* __restrict__ rig, float* __restrict__ partials,
              float* __restrict__ out) {
    __shared__ __align__(16) short bufs[2][16 * 2048];   // 2 x 64 KB chunk buffers
    __shared__ __align__(16) float ens[K_CODES];         // 4 KB exact fp32 ||e||^2
    __shared__ float xnorm[QT];
    __shared__ float rd1[QT];
    __shared__ float rd2[QT];
    __shared__ int   ri[QT];
    __shared__ int   flist[QT];
    __shared__ __align__(16) float xqf[CDIM];
    __shared__ float wdd[8];
    __shared__ int   wii[8];
    __shared__ float spw[4];
    __shared__ int   nflag;
    float* tile = (float*)bufs;      // 64*72 f32 epilogue transpose, aliases bufs

    const int tid  = threadIdx.x;
    const int lane = tid & 63;
    const int w    = tid >> 6;       // 0..7
    const int quad = lane >> 4;
    const int col  = lane & 15;

    const int n0  = blockIdx.x * QT;
    const int b   = n0 >> 10;
    const int hw0 = n0 & 1023;        // 256-aligned

    auto stage_async = [&](int c, int bsel) {
        const short* src = btab + c * (16 * 2048);
#pragma unroll
        for (int i = 0; i < 8; ++i) {
            int idx = i * 512 + tid;                  // 16B units, 0..4095
            gload_lds16(&src[idx * 8], (void*)&bufs[bsel][idx * 8]);
        }
    };

    stage_async(0, 0);
    if (tid < 256) gload_lds16(&enorm[tid * 4], (void*)&ens[tid * 4]);

    // A fragments straight from global; hi/lo bf16 split in regs; ||x||^2 via shfl.
    const float* xb = x + b * (CDIM * HW_SZ) + hw0 + col;
    short8 afr[2][2][2];     // [rt][kc][hi/lo]
#pragma unroll
    for (int rt = 0; rt < 2; ++rt) {
        float nloc = 0.f;
#pragma unroll
        for (int kc = 0; kc < 2; ++kc) {
#pragma unroll
            for (int j = 0; j < 8; ++j) {
                int c0 = (kc * 4 + quad) * 8 + j;
                float v = xb[c0 * HW_SZ + w * 32 + rt * 16];
                unsigned short hh = f2bf(v);
                afr[rt][kc][0][j] = (short)hh;
                afr[rt][kc][1][j] = (short)f2bf(v - bf2f(hh));
                nloc = __builtin_fmaf(v, v, nloc);
            }
        }
        nloc += __shfl_xor(nloc, 16, 64);
        nloc += __shfl_xor(nloc, 32, 64);
        if (quad == 0) xnorm[w * 32 + rt * 16 + col] = nloc;
    }

    float d1[8], d2[8];
    int   i1[8];
#pragma unroll
    for (int t = 0; t < 8; ++t) { d1[t] = 3.4e38f; d2[t] = 3.4e38f; i1[t] = 0; }

    __syncthreads();   // chunk 0 + ens + xnorm ready

    for (int c = 0; c < NCHUNK; ++c) {
        if (c + 1 < NCHUNK) stage_async(c + 1, (c + 1) & 1);
        const short* bs = &bufs[c & 1][0];
        const int cbase = c * 256;

        short8 Ba[4], Bb[4];          // [kc0hi, kc0lo, kc1hi, kc1lo]
        float  ena, enb;
        auto LDB = [&](short8 (&B)[4], float& en, int ctl) {
            const short* fp = bs + ctl * 2048 + lane * 8;
            B[0] = *(const short8*)(fp);
            B[1] = *(const short8*)(fp + 512);
            B[2] = *(const short8*)(fp + 1024);
            B[3] = *(const short8*)(fp + 1536);
            en   = ens[cbase + ctl * 16 + col];
        };
        auto COMP = [&](const short8 (&B)[4], float en, int mycode) {
#pragma unroll
            for (int rt = 0; rt < 2; ++rt) {
                f32x4 a0 = {0.f, 0.f, 0.f, 0.f};
                f32x4 a1 = {0.f, 0.f, 0.f, 0.f};
                a0 = __builtin_amdgcn_mfma_f32_16x16x32_bf16(afr[rt][0][1], B[0], a0, 0, 0, 0);
                a1 = __builtin_amdgcn_mfma_f32_16x16x32_bf16(afr[rt][1][1], B[2], a1, 0, 0, 0);
                a0 = __builtin_amdgcn_mfma_f32_16x16x32_bf16(afr[rt][0][0], B[1], a0, 0, 0, 0);
                a1 = __builtin_amdgcn_mfma_f32_16x16x32_bf16(afr[rt][1][0], B[3], a1, 0, 0, 0);
                a0 = __builtin_amdgcn_mfma_f32_16x16x32_bf16(afr[rt][0][0], B[0], a0, 0, 0, 0);
                a1 = __builtin_amdgcn_mfma_f32_16x16x32_bf16(afr[rt][1][0], B[2], a1, 0, 0, 0);
#pragma unroll
                for (int reg = 0; reg < 4; ++reg) {
                    int t = rt * 4 + reg;
                    float dot = a0[reg] + a1[reg];
                    float d   = __builtin_fmaf(dot, -2.f, en);
                    float d1o = d1[t];
                    d2[t] = __builtin_amdgcn_fmed3f(d, d1o, d2[t]);
                    d1[t] = fminf(d, d1o);
                    i1[t] = (d < d1o) ? mycode : i1[t];
                }
            }
        };

        LDB(Ba, ena, 0);
#pragma unroll
        for (int ctl = 0; ctl < 16; ctl += 2) {
            LDB(Bb, enb, ctl + 1);
            COMP(Ba, ena, cbase + ctl * 16 + col);
            if (ctl + 2 < 16) LDB(Ba, ena, ctl + 2);
            COMP(Bb, enb, cbase + (ctl + 1) * 16 + col);
        }
        __syncthreads();
    }

    // reduce across 16 cols per query row (codes ascend with col: lex-min ok)
#pragma unroll
    for (int t = 0; t < 8; ++t) {
        float a1 = d1[t], a2 = d2[t];
        int ai = i1[t];
#pragma unroll
        for (int off = 1; off < 16; off <<= 1) {
            float o1 = __shfl_xor(a1, off, 64);
            float o2 = __shfl_xor(a2, off, 64);
            int   oi = __shfl_xor(ai, off, 64);
            if (o1 < a1 || (o1 == a1 && oi < ai)) {
                float loser = a1; a2 = fminf(fminf(a2, o2), loser); a1 = o1; ai = oi;
            } else {
                a2 = fminf(fminf(a2, o2), o1);
            }
        }
        d1[t] = a1; d2[t] = a2; i1[t] = ai;
    }

    if (tid == 0) nflag = 0;
    if (col == 0) {
#pragma unroll
        for (int rt = 0; rt < 2; ++rt)
#pragma unroll
            for (int reg = 0; reg < 4; ++reg) {
                int t = rt * 4 + reg;
                int m = w * 32 + rt * 16 + quad * 4 + reg;
                rd1[m] = d1[t];
                rd2[m] = d2[t];
                ri [m] = i1[t];
            }
    }
    __syncthreads();

    // flag queries with margin < TAU for exact in-block re-solve
    if (tid < QT) {
        if (rd2[tid] - rd1[tid] < TAU) {
            int slot = atomicAdd(&nflag, 1);
            flist[slot] = tid;
        }
    }
    __syncthreads();

    // ---- in-block exact fp32 rescue (avg nflag ~1 per block) ----
    for (int f = 0; f < nflag; ++f) {
        const int q = flist[f];
        if (tid < CDIM) xqf[tid] = x[b * (CDIM * HW_SZ) + tid * HW_SZ + hw0 + q];
        __syncthreads();
        float dm = 3.4e38f; int im = 0;
        for (int cd = 0; cd < 2; ++cd) {
            const int k = tid + cd * 512;            // codes ascend with cd
            const float4* er = (const float4*)(emb + k * CDIM);
            const float4* xr = (const float4*)xqf;
            float dot = 0.f;
#pragma unroll 4
            for (int c4 = 0; c4 < 16; ++c4) {
                float4 e = er[c4], xv = xr[c4];
                dot += e.x * xv.x + e.y * xv.y + e.z * xv.z + e.w * xv.w;
            }
            float d = ens[k] - 2.f * dot;            // exact fp32
            if (d < dm) { dm = d; im = k; }
        }
#pragma unroll
        for (int off = 1; off < 64; off <<= 1) {
            float od = __shfl_xor(dm, off, 64);
            int   oi = __shfl_xor(im, off, 64);
            if (od < dm || (od == dm && oi < im)) { dm = od; im = oi; }
        }
        if (lane == 0) { wdd[w] = dm; wii[w] = im; }
        __syncthreads();
        if (tid == 0) {
            float bd = wdd[0]; int bi = wii[0];
#pragma unroll
            for (int ww = 1; ww < 8; ++ww)
                if (wdd[ww] < bd || (wdd[ww] == bd && wii[ww] < bi)) { bd = wdd[ww]; bi = wii[ww]; }
            rd1[q] = bd; ri[q] = bi;                 // final exact result
        }
        __syncthreads();
    }

    // ---- FINAL-index writeback + SSE partial (no global atomics) ----
    if (tid < QT) {
        rig[n0 + tid] = ri[tid];                     // for k_final's LDS hist
        float sp = rd1[tid] + xnorm[tid];            // ||q-x||^2 (exact for rescued)
#pragma unroll
        for (int off = 32; off; off >>= 1) sp += __shfl_down(sp, off, 64);
        if (lane == 0) spw[w] = sp;
    }
    __syncthreads();
    if (tid == 0) partials[blockIdx.x] = spw[0] + spw[1] + spw[2] + spw[3];

    // ---- output write: four 64-query quarters; EXACT fp32 emb gather ----
#pragma unroll
    for (int h = 0; h < 4; ++h) {
        {   // gather: thread = (q = tid>>3, j8 = tid&7) -> 8 dims from emb row
            int q = tid >> 3, j8 = tid & 7;
            int code = ri[h * 64 + q];
            const float4* er = (const float4*)(emb + code * CDIM + j8 * 8);
            float4 e0 = er[0], e1 = er[1];
            float* dst = &tile[q * 72 + j8 * 8];
            *(float4*)&dst[0] = e0;
            *(float4*)&dst[4] = e1;
        }
        __syncthreads();
        {   // transposed coalesced write
            int c = tid >> 3;
            float* ob = out + b * (CDIM * HW_SZ) + c * HW_SZ + hw0 + h * 64;
#pragma unroll
            for (int p = 0; p < 2; ++p) {
                int q = ((tid & 7) + p * 8) * 4;   // 0..60
                float4 v;
                v.x = tile[(q + 0) * 72 + c];
                v.y = tile[(q + 1) * 72 + c];
                v.z = tile[(q + 2) * 72 + c];
                v.w = tile[(q + 3) * 72 + c];
                *(float4*)&ob[q] = v;
            }
        }
        if (h < 3) __syncthreads();
    }
}

// --------------------------------------------------------------- k_final ----
// 1 block x 1024 thr. Builds the 1024-bin histogram from FINAL indices in
// LDS (no cross-XCD atomic contention), then entropy + loss.
__global__ __launch_bounds__(1024, 1)
void k_final(const int* __restrict__ rig, const float* __restrict__ partials,
             float* __restrict__ out) {
    __shared__ unsigned int lhist[K_CODES];
    __shared__ float fin[32];
    int tid = threadIdx.x;   // 0..1023

    if (tid < K_CODES) lhist[tid] = 0u;
    __syncthreads();
#pragma unroll
    for (int i = 0; i < N_TOTAL / 1024; ++i)     // 64 coalesced passes
        atomicAdd(&lhist[rig[i * 1024 + tid]], 1u);
    __syncthreads();

    float ss = (tid < 256) ? partials[tid] : 0.f;
    float p  = (float)lhist[tid] * (1.0f / 65536.0f);
    float s  = p * logf(p + 1e-10f);
#pragma unroll
    for (int off = 32; off; off >>= 1) {
        ss += __shfl_down(ss, off, 64);
        s  += __shfl_down(s, off, 64);
    }
    if ((tid & 63) == 0) { fin[tid >> 6] = ss; fin[16 + (tid >> 6)] = s; }
    __syncthreads();
    if (tid == 0) {
        float sse = 0.f, ent = 0.f;
#pragma unroll
        for (int i = 0; i < 16; ++i) { sse += fin[i]; ent += fin[16 + i]; }
        out[OUT_ELEMS]     = 1.25f * sse * (1.0f / (float)OUT_ELEMS);  // loss
        out[OUT_ELEMS + 1] = expf(-ent);                                // perplexity
    }
}

// ---------------------------------------------------------------- launch ----
extern "C" void kernel_launch(void* const* d_in, const int* in_sizes, int n_in,
                              void* d_out, int out_size, void* d_ws, size_t ws_size,
                              hipStream_t stream) {
    const float* x   = (const float*)d_in[0];
    const float* emb = (const float*)d_in[1];
    float* out = (float*)d_out;
    char* ws = (char*)d_ws;
    float*        enorm    = (float*)(ws);
    float*        partials = (float*)(ws + 8192);
    short*        btab     = (short*)(ws + 12288);
    int*          rig      = (int*)  (ws + 274432);

    k_prep  <<<64, 256, 0, stream>>>(emb, enorm, btab);
    k_argmin<<<N_TOTAL / QT, 512, 0, stream>>>(x, emb, btab, enorm, rig, partials, out);
    k_final <<<1, 1024, 0, stream>>>(rig, partials, out);
}

// Round 9
// 153.885 us; speedup vs baseline: 1.1019x; 1.0011x over previous
//
#include <hip/hip_runtime.h>

// Problem constants
#define N_TOTAL   65536   // B*H*W = 64*32*32
#define HW_SZ     1024    // H*W
#define CDIM      64      // embedding dim (= C)
#define K_CODES   1024
#define OUT_ELEMS 4194304 // 64*64*32*32
#define QT        256     // queries per block (16 per wave, 16 waves)
#define NCHUNK    4       // 4 chunks of 256 codes (64 KB each), double-buffered
#define TAU       0.004f  // rescue margin (> 2x analytic bf16x3 error bound ~1.5e-3)

// ws layout (bytes):
//   0       : enorm[1024]   f32
//   4096    : hist[1024]    u32
//   8192    : partials[256] f32
//   12288   : btab (256 KB) bf16 hi/lo table in MFMA B-FRAGMENT order:
//             short index = ct*2048 + kc*1024 + h*512 + lane*8 + j
//             code = ct*16 + (lane&15), dim = (kc*4 + (lane>>4))*8 + j

typedef __attribute__((ext_vector_type(8))) short short8;
typedef __attribute__((ext_vector_type(4))) float f32x4;

__device__ __forceinline__ unsigned short f2bf(float x) {
    unsigned u = __float_as_uint(x);
    return (unsigned short)((u + 0x7FFFu + ((u >> 16) & 1u)) >> 16);   // RNE
}
__device__ __forceinline__ float bf2f(unsigned short h) {
    return __uint_as_float(((unsigned)h) << 16);
}
__device__ __forceinline__ void gload_lds16(const void* g, void* l) {
    __builtin_amdgcn_global_load_lds(
        (const __attribute__((address_space(1))) void*)g,
        (__attribute__((address_space(3))) void*)l, 16, 0, 0);
}

// ---------------------------------------------------------------- k_prep ----
// Writes ||e||^2, the frag-ordered bf16 hi/lo table, zeroes hist.
__global__ void k_prep(const float* __restrict__ emb, float* __restrict__ enorm,
                       short* __restrict__ btab, unsigned int* __restrict__ hist) {
    int gid = blockIdx.x * 256 + threadIdx.x;        // 0..16383
    int r  = gid >> 4;           // code 0..1023
    int d0 = (gid & 15) * 4;     // dim base 0..60
    float4 v = *(const float4*)(emb + gid * 4);
    float s = v.x * v.x + v.y * v.y + v.z * v.z + v.w * v.w;
#pragma unroll
    for (int off = 1; off < 16; off <<= 1) s += __shfl_xor(s, off, 64);
    if ((gid & 15) == 0) enorm[r] = s;

    float vv[4] = {v.x, v.y, v.z, v.w};
    short h[4], l[4];
#pragma unroll
    for (int j = 0; j < 4; ++j) {
        unsigned short hh = f2bf(vv[j]);
        h[j] = (short)hh;
        l[j] = (short)f2bf(vv[j] - bf2f(hh));
    }
    int base = (r >> 4) * 2048 + (d0 >> 5) * 1024
             + ((((d0 >> 3) & 3) * 16 + (r & 15)) * 8) + (d0 & 7);
    *(short4*)&btab[base]       = make_short4(h[0], h[1], h[2], h[3]);
    *(short4*)&btab[base + 512] = make_short4(l[0], l[1], l[2], l[3]);

    if (gid < K_CODES) hist[gid] = 0u;
}

// -------------------------------------------------------------- k_argmin ----
// 1024 thr = 16 waves (4 waves/SIMD — TLP dose 3 of the 1->2->4 curve).
// QT=256 queries/block (16 per wave), grid 256 = 1 block/CU. Code table
// LDS-resident in 4 double-buffered 256-code chunks; explicit 2-stage
// register pipeline (Ba/Bb) in the ctl loop. bf16x3 distance, top-2
// tracking, TAU-margin exact fp32 rescue, fused epilogue with hist global
// atomics (spread over kernel lifetime) + fp32 emb gather out-write.
__global__ __launch_bounds__(1024, 1)
void k_argmin(const float* __restrict__ x, const float* __restrict__ emb,
              const short* __restrict__ btab, const float* __restrict__ enorm,
              unsigned int* __restrict__ hist, float* __restrict__ partials,
              float* __restrict__ out) {
    __shared__ __align__(16) short bufs[2][16 * 2048];   // 2 x 64 KB chunk buffers
    __shared__ __align__(16) float ens[K_CODES];         // 4 KB exact fp32 ||e||^2
    __shared__ float xnorm[QT];
    __shared__ float rd1[QT];
    __shared__ float rd2[QT];
    __shared__ int   ri[QT];
    __shared__ int   flist[QT];
    __shared__ __align__(16) float xqf[CDIM];
    __shared__ float wdd[16];
    __shared__ int   wii[16];
    __shared__ float spw[4];
    __shared__ int   nflag;
    float* tile = (float*)bufs;      // 64 x 73 f32 epilogue transpose, aliases bufs

    const int tid  = threadIdx.x;    // 0..1023
    const int lane = tid & 63;
    const int w    = tid >> 6;       // 0..15
    const int quad = lane >> 4;
    const int col  = lane & 15;

    const int n0  = blockIdx.x * QT;
    const int b   = n0 >> 10;
    const int hw0 = n0 & 1023;        // 256-aligned

    auto stage_async = [&](int c, int bsel) {
        const short* src = btab + c * (16 * 2048);
#pragma unroll
        for (int i = 0; i < 4; ++i) {
            int idx = i * 1024 + tid;                 // 16B units, 0..4095
            gload_lds16(&src[idx * 8], (void*)&bufs[bsel][idx * 8]);
        }
    };

    stage_async(0, 0);
    if (tid < 256) gload_lds16(&enorm[tid * 4], (void*)&ens[tid * 4]);

    // A fragments straight from global; hi/lo bf16 split in regs; ||x||^2 via shfl.
    // Wave w owns queries n0 + w*16 .. +15; this lane's query = w*16 + col.
    const float* xb = x + b * (CDIM * HW_SZ) + hw0 + w * 16 + col;
    short8 afr[2][2];        // [kc][hi/lo]
    float nloc = 0.f;
#pragma unroll
    for (int kc = 0; kc < 2; ++kc) {
#pragma unroll
        for (int j = 0; j < 8; ++j) {
            int c0 = (kc * 4 + quad) * 8 + j;
            float v = xb[c0 * HW_SZ];
            unsigned short hh = f2bf(v);
            afr[kc][0][j] = (short)hh;
            afr[kc][1][j] = (short)f2bf(v - bf2f(hh));
            nloc = __builtin_fmaf(v, v, nloc);
        }
    }
    nloc += __shfl_xor(nloc, 16, 64);
    nloc += __shfl_xor(nloc, 32, 64);
    if (quad == 0) xnorm[w * 16 + col] = nloc;

    float d1[4], d2[4];
    int   i1[4];
#pragma unroll
    for (int t = 0; t < 4; ++t) { d1[t] = 3.4e38f; d2[t] = 3.4e38f; i1[t] = 0; }

    __syncthreads();   // chunk 0 + ens + xnorm ready

    for (int c = 0; c < NCHUNK; ++c) {
        if (c + 1 < NCHUNK) stage_async(c + 1, (c + 1) & 1);
        const short* bs = &bufs[c & 1][0];
        const int cbase = c * 256;

        short8 Ba[4], Bb[4];          // [kc0hi, kc0lo, kc1hi, kc1lo]
        float  ena, enb;
        auto LDB = [&](short8 (&B)[4], float& en, int ctl) {
            const short* fp = bs + ctl * 2048 + lane * 8;
            B[0] = *(const short8*)(fp);
            B[1] = *(const short8*)(fp + 512);
            B[2] = *(const short8*)(fp + 1024);
            B[3] = *(const short8*)(fp + 1536);
            en   = ens[cbase + ctl * 16 + col];
        };
        auto COMP = [&](const short8 (&B)[4], float en, int mycode) {
            // two independent 3-deep chains (kc0, kc1), fp32-summed
            f32x4 a0 = {0.f, 0.f, 0.f, 0.f};
            f32x4 a1 = {0.f, 0.f, 0.f, 0.f};
            a0 = __builtin_amdgcn_mfma_f32_16x16x32_bf16(afr[0][1], B[0], a0, 0, 0, 0);
            a1 = __builtin_amdgcn_mfma_f32_16x16x32_bf16(afr[1][1], B[2], a1, 0, 0, 0);
            a0 = __builtin_amdgcn_mfma_f32_16x16x32_bf16(afr[0][0], B[1], a0, 0, 0, 0);
            a1 = __builtin_amdgcn_mfma_f32_16x16x32_bf16(afr[1][0], B[3], a1, 0, 0, 0);
            a0 = __builtin_amdgcn_mfma_f32_16x16x32_bf16(afr[0][0], B[0], a0, 0, 0, 0);
            a1 = __builtin_amdgcn_mfma_f32_16x16x32_bf16(afr[1][0], B[2], a1, 0, 0, 0);
#pragma unroll
            for (int reg = 0; reg < 4; ++reg) {
                float dot = a0[reg] + a1[reg];
                float d   = __builtin_fmaf(dot, -2.f, en);
                float d1o = d1[reg];
                d2[reg] = __builtin_amdgcn_fmed3f(d, d1o, d2[reg]);
                d1[reg] = fminf(d, d1o);
                i1[reg] = (d < d1o) ? mycode : i1[reg];
            }
        };

        LDB(Ba, ena, 0);
#pragma unroll
        for (int ctl = 0; ctl < 16; ctl += 2) {
            LDB(Bb, enb, ctl + 1);
            COMP(Ba, ena, cbase + ctl * 16 + col);
            if (ctl + 2 < 16) LDB(Ba, ena, ctl + 2);
            COMP(Bb, enb, cbase + (ctl + 1) * 16 + col);
        }
        __syncthreads();
    }

    // reduce across 16 cols per query row (codes ascend with col: lex-min ok)
#pragma unroll
    for (int t = 0; t < 4; ++t) {
        float a1 = d1[t], a2 = d2[t];
        int ai = i1[t];
#pragma unroll
        for (int off = 1; off < 16; off <<= 1) {
            float o1 = __shfl_xor(a1, off, 64);
            float o2 = __shfl_xor(a2, off, 64);
            int   oi = __shfl_xor(ai, off, 64);
            if (o1 < a1 || (o1 == a1 && oi < ai)) {
                float loser = a1; a2 = fminf(fminf(a2, o2), loser); a1 = o1; ai = oi;
            } else {
                a2 = fminf(fminf(a2, o2), o1);
            }
        }
        d1[t] = a1; d2[t] = a2; i1[t] = ai;
    }

    if (tid == 0) nflag = 0;
    if (col == 0) {
#pragma unroll
        for (int reg = 0; reg < 4; ++reg) {
            int m = w * 16 + quad * 4 + reg;
            rd1[m] = d1[reg];
            rd2[m] = d2[reg];
            ri [m] = i1[reg];
        }
    }
    __syncthreads();

    // flag queries with margin < TAU for exact in-block re-solve
    if (tid < QT) {
        if (rd2[tid] - rd1[tid] < TAU) {
            int slot = atomicAdd(&nflag, 1);
            flist[slot] = tid;
        }
    }
    __syncthreads();

    // ---- in-block exact fp32 rescue (avg nflag ~1 per block) ----
    for (int f = 0; f < nflag; ++f) {
        const int q = flist[f];
        if (tid < CDIM) xqf[tid] = x[b * (CDIM * HW_SZ) + tid * HW_SZ + hw0 + q];
        __syncthreads();
        // 1024 threads: one code per thread, single pass
        const int k = tid;
        const float4* er = (const float4*)(emb + k * CDIM);
        const float4* xr = (const float4*)xqf;
        float dot = 0.f;
#pragma unroll 4
        for (int c4 = 0; c4 < 16; ++c4) {
            float4 e = er[c4], xv = xr[c4];
            dot += e.x * xv.x + e.y * xv.y + e.z * xv.z + e.w * xv.w;
        }
        float dm = ens[k] - 2.f * dot;               // exact fp32
        int   im = k;
#pragma unroll
        for (int off = 1; off < 64; off <<= 1) {
            float od = __shfl_xor(dm, off, 64);
            int   oi = __shfl_xor(im, off, 64);
            if (od < dm || (od == dm && oi < im)) { dm = od; im = oi; }
        }
        if (lane == 0) { wdd[w] = dm; wii[w] = im; }
        __syncthreads();
        if (tid == 0) {
            float bd = wdd[0]; int bi = wii[0];
#pragma unroll
            for (int ww = 1; ww < 16; ++ww)
                if (wdd[ww] < bd || (wdd[ww] == bd && wii[ww] < bi)) { bd = wdd[ww]; bi = wii[ww]; }
            rd1[q] = bd; ri[q] = bi;                 // final exact result
        }
        __syncthreads();
    }

    // ---- epilogue on FINAL indices: hist atomics (staggered, cheap) + SSE ----
    if (tid < QT) {
        int ai = ri[tid];
        atomicAdd(&hist[ai], 1u);
        float sp = rd1[tid] + xnorm[tid];            // ||q-x||^2 (exact for rescued)
#pragma unroll
        for (int off = 32; off; off >>= 1) sp += __shfl_down(sp, off, 64);
        if (lane == 0) spw[tid >> 6] = sp;
    }
    __syncthreads();
    if (tid == 0) partials[blockIdx.x] = spw[0] + spw[1] + spw[2] + spw[3];

    // ---- output write: four 64-query quarters; EXACT fp32 emb gather ----
#pragma unroll
    for (int h = 0; h < 4; ++h) {
        {   // gather: thread = (q = tid>>4, j4 = tid&15) -> 4 dims from emb row
            int q = tid >> 4, j4 = tid & 15;
            int code = ri[h * 64 + q];
            float4 e = *(const float4*)(emb + code * CDIM + j4 * 4);
            *(float4*)&tile[q * 73 + j4 * 4] = e;
        }
        __syncthreads();
        {   // transposed coalesced write (tile stride 73: odd -> ~2-way banks)
            int c = tid >> 4, s = tid & 15;          // c 0..63, s 0..15
            int q = s * 4;
            float4 v;
            v.x = tile[(q + 0) * 73 + c];
            v.y = tile[(q + 1) * 73 + c];
            v.z = tile[(q + 2) * 73 + c];
            v.w = tile[(q + 3) * 73 + c];
            *(float4*)&out[b * (CDIM * HW_SZ) + c * HW_SZ + hw0 + h * 64 + q] = v;
        }
        if (h < 3) __syncthreads();
    }
}

// --------------------------------------------------------------- k_final ----
// 1 block x 256 thr; reads partials (256) + hist (1024). Tiny.
__global__ void k_final(const float* __restrict__ partials,
                        const unsigned int* __restrict__ hist,
                        float* __restrict__ out) {
    int tid = threadIdx.x;   // 256
    float ss = partials[tid];
    float s = 0.f;
#pragma unroll
    for (int i = 0; i < 4; ++i) {
        float p = (float)hist[i * 256 + tid] * (1.0f / 65536.0f);
        s += p * logf(p + 1e-10f);
    }
    __shared__ float fin[8];
#pragma unroll
    for (int off = 32; off; off >>= 1) {
        ss += __shfl_down(ss, off, 64);
        s  += __shfl_down(s, off, 64);
    }
    if ((tid & 63) == 0) { fin[tid >> 6] = ss; fin[4 + (tid >> 6)] = s; }
    __syncthreads();
    if (tid == 0) {
        float sse = fin[0] + fin[1] + fin[2] + fin[3];
        float ent = fin[4] + fin[5] + fin[6] + fin[7];
        out[OUT_ELEMS]     = 1.25f * sse * (1.0f / (float)OUT_ELEMS);  // loss
        out[OUT_ELEMS + 1] = expf(-ent);                                // perplexity
    }
}

// ---------------------------------------------------------------- launch ----
extern "C" void kernel_launch(void* const* d_in, const int* in_sizes, int n_in,
                              void* d_out, int out_size, void* d_ws, size_t ws_size,
                              hipStream_t stream) {
    const float* x   = (const float*)d_in[0];
    const float* emb = (const float*)d_in[1];
    float* out = (float*)d_out;
    char* ws = (char*)d_ws;
    float*        enorm    = (float*)(ws);
    unsigned int* hist     = (unsigned int*)(ws + 4096);
    float*        partials = (float*)(ws + 8192);
    short*        btab     = (short*)(ws + 12288);

    k_prep  <<<64, 256, 0, stream>>>(emb, enorm, btab, hist);
    k_argmin<<<N_TOTAL / QT, 1024, 0, stream>>>(x, emb, btab, enorm, hist, partials, out);
    k_final <<<1, 256, 0, stream>>>(partials, hist, out);
}

// Round 10
// 142.484 us; speedup vs baseline: 1.1901x; 1.0800x over previous
//
#include <hip/hip_runtime.h>

// Problem constants
#define N_TOTAL   65536   // B*H*W = 64*32*32
#define HW_SZ     1024    // H*W
#define CDIM      64      // embedding dim (= C)
#define K_CODES   1024
#define OUT_ELEMS 4194304 // 64*64*32*32
#define QT        128     // queries per block (16 per wave, 8 waves)
#define NCHUNK    8       // 8 chunks of 128 codes (32 KB each), double-buffered
#define TAU       0.004f  // rescue margin (> 2x analytic bf16x3 error bound ~1.5e-3)

// ws layout (bytes):
//   0       : enorm[1024]   f32
//   4096    : hist[1024]    u32
//   8192    : partials[512] f32
//   12288   : btab (256 KB) bf16 hi/lo table in MFMA B-FRAGMENT order:
//             short index = ct*2048 + kc*1024 + h*512 + lane*8 + j
//             code = ct*16 + (lane&15), dim = (kc*4 + (lane>>4))*8 + j

typedef __attribute__((ext_vector_type(8))) short short8;
typedef __attribute__((ext_vector_type(4))) float f32x4;

__device__ __forceinline__ unsigned short f2bf(float x) {
    unsigned u = __float_as_uint(x);
    return (unsigned short)((u + 0x7FFFu + ((u >> 16) & 1u)) >> 16);   // RNE
}
__device__ __forceinline__ float bf2f(unsigned short h) {
    return __uint_as_float(((unsigned)h) << 16);
}
__device__ __forceinline__ void gload_lds16(const void* g, void* l) {
    __builtin_amdgcn_global_load_lds(
        (const __attribute__((address_space(1))) void*)g,
        (__attribute__((address_space(3))) void*)l, 16, 0, 0);
}

// ---------------------------------------------------------------- k_prep ----
// Writes ||e||^2, the frag-ordered bf16 hi/lo table, zeroes hist.
__global__ void k_prep(const float* __restrict__ emb, float* __restrict__ enorm,
                       short* __restrict__ btab, unsigned int* __restrict__ hist) {
    int gid = blockIdx.x * 256 + threadIdx.x;        // 0..16383
    int r  = gid >> 4;           // code 0..1023
    int d0 = (gid & 15) * 4;     // dim base 0..60
    float4 v = *(const float4*)(emb + gid * 4);
    float s = v.x * v.x + v.y * v.y + v.z * v.z + v.w * v.w;
#pragma unroll
    for (int off = 1; off < 16; off <<= 1) s += __shfl_xor(s, off, 64);
    if ((gid & 15) == 0) enorm[r] = s;

    float vv[4] = {v.x, v.y, v.z, v.w};
    short h[4], l[4];
#pragma unroll
    for (int j = 0; j < 4; ++j) {
        unsigned short hh = f2bf(vv[j]);
        h[j] = (short)hh;
        l[j] = (short)f2bf(vv[j] - bf2f(hh));
    }
    int base = (r >> 4) * 2048 + (d0 >> 5) * 1024
             + ((((d0 >> 3) & 3) * 16 + (r & 15)) * 8) + (d0 & 7);
    *(short4*)&btab[base]       = make_short4(h[0], h[1], h[2], h[3]);
    *(short4*)&btab[base + 512] = make_short4(l[0], l[1], l[2], l[3]);

    if (gid < K_CODES) hist[gid] = 0u;
}

// -------------------------------------------------------------- k_argmin ----
// TLP dose 3 in the proven (512,2) envelope: 512 thr = 8 waves, QT=128
// (1 query-tile of 16 per wave), grid 512 = 2 blocks/CU -> 16 waves/CU =
// 4 waves/SIMD. LDS ~70 KB (two blocks fit). Code table LDS-resident in 8
// double-buffered 128-code chunks (32 KB); explicit Ba/Bb register pipeline.
// bf16x3 distance, top-2 tracking, TAU exact fp32 rescue, fused epilogue
// (hist atomics + fp32 emb gather out-write, stride-73 tile), tiny k_final.
__global__ __launch_bounds__(512, 2)
void k_argmin(const float* __restrict__ x, const float* __restrict__ emb,
              const short* __restrict__ btab, const float* __restrict__ enorm,
              unsigned int* __restrict__ hist, float* __restrict__ partials,
              float* __restrict__ out) {
    __shared__ __align__(16) short bufs[2][8 * 2048];    // 2 x 32 KB chunk buffers
    __shared__ __align__(16) float ens[K_CODES];         // 4 KB exact fp32 ||e||^2
    __shared__ float xnorm[QT];
    __shared__ float rd1[QT];
    __shared__ float rd2[QT];
    __shared__ int   ri[QT];
    __shared__ int   flist[QT];
    __shared__ __align__(16) float xqf[CDIM];
    __shared__ float wdd[8];
    __shared__ int   wii[8];
    __shared__ float spw[2];
    __shared__ int   nflag;
    float* tile = (float*)bufs;      // 64 x 73 f32 epilogue transpose, aliases bufs

    const int tid  = threadIdx.x;    // 0..511
    const int lane = tid & 63;
    const int w    = tid >> 6;       // 0..7
    const int quad = lane >> 4;
    const int col  = lane & 15;

    const int n0  = blockIdx.x * QT;
    const int b   = n0 >> 10;
    const int hw0 = n0 & 1023;        // 128-aligned

    auto stage_async = [&](int c, int bsel) {
        const short* src = btab + c * (8 * 2048);
#pragma unroll
        for (int i = 0; i < 4; ++i) {
            int idx = i * 512 + tid;                  // 16B units, 0..2047
            gload_lds16(&src[idx * 8], (void*)&bufs[bsel][idx * 8]);
        }
    };

    stage_async(0, 0);
    if (tid < 256) gload_lds16(&enorm[tid * 4], (void*)&ens[tid * 4]);

    // A fragments straight from global; hi/lo bf16 split in regs; ||x||^2 via shfl.
    // Wave w owns queries n0 + w*16 .. +15; this lane's query = w*16 + col.
    const float* xb = x + b * (CDIM * HW_SZ) + hw0 + w * 16 + col;
    short8 afr[2][2];        // [kc][hi/lo]
    float nloc = 0.f;
#pragma unroll
    for (int kc = 0; kc < 2; ++kc) {
#pragma unroll
        for (int j = 0; j < 8; ++j) {
            int c0 = (kc * 4 + quad) * 8 + j;
            float v = xb[c0 * HW_SZ];
            unsigned short hh = f2bf(v);
            afr[kc][0][j] = (short)hh;
            afr[kc][1][j] = (short)f2bf(v - bf2f(hh));
            nloc = __builtin_fmaf(v, v, nloc);
        }
    }
    nloc += __shfl_xor(nloc, 16, 64);
    nloc += __shfl_xor(nloc, 32, 64);
    if (quad == 0) xnorm[w * 16 + col] = nloc;

    float d1[4], d2[4];
    int   i1[4];
#pragma unroll
    for (int t = 0; t < 4; ++t) { d1[t] = 3.4e38f; d2[t] = 3.4e38f; i1[t] = 0; }

    __syncthreads();   // chunk 0 + ens + xnorm ready

    for (int c = 0; c < NCHUNK; ++c) {
        if (c + 1 < NCHUNK) stage_async(c + 1, (c + 1) & 1);
        const short* bs = &bufs[c & 1][0];
        const int cbase = c * 128;

        short8 Ba[4], Bb[4];          // [kc0hi, kc0lo, kc1hi, kc1lo]
        float  ena, enb;
        auto LDB = [&](short8 (&B)[4], float& en, int ctl) {
            const short* fp = bs + ctl * 2048 + lane * 8;
            B[0] = *(const short8*)(fp);
            B[1] = *(const short8*)(fp + 512);
            B[2] = *(const short8*)(fp + 1024);
            B[3] = *(const short8*)(fp + 1536);
            en   = ens[cbase + ctl * 16 + col];
        };
        auto COMP = [&](const short8 (&B)[4], float en, int mycode) {
            // two independent 3-deep chains (kc0, kc1), fp32-summed
            f32x4 a0 = {0.f, 0.f, 0.f, 0.f};
            f32x4 a1 = {0.f, 0.f, 0.f, 0.f};
            a0 = __builtin_amdgcn_mfma_f32_16x16x32_bf16(afr[0][1], B[0], a0, 0, 0, 0);
            a1 = __builtin_amdgcn_mfma_f32_16x16x32_bf16(afr[1][1], B[2], a1, 0, 0, 0);
            a0 = __builtin_amdgcn_mfma_f32_16x16x32_bf16(afr[0][0], B[1], a0, 0, 0, 0);
            a1 = __builtin_amdgcn_mfma_f32_16x16x32_bf16(afr[1][0], B[3], a1, 0, 0, 0);
            a0 = __builtin_amdgcn_mfma_f32_16x16x32_bf16(afr[0][0], B[0], a0, 0, 0, 0);
            a1 = __builtin_amdgcn_mfma_f32_16x16x32_bf16(afr[1][0], B[2], a1, 0, 0, 0);
#pragma unroll
            for (int reg = 0; reg < 4; ++reg) {
                float dot = a0[reg] + a1[reg];
                float d   = __builtin_fmaf(dot, -2.f, en);
                float d1o = d1[reg];
                d2[reg] = __builtin_amdgcn_fmed3f(d, d1o, d2[reg]);
                d1[reg] = fminf(d, d1o);
                i1[reg] = (d < d1o) ? mycode : i1[reg];
            }
        };

        LDB(Ba, ena, 0);
#pragma unroll
        for (int ctl = 0; ctl < 8; ctl += 2) {
            LDB(Bb, enb, ctl + 1);
            COMP(Ba, ena, cbase + ctl * 16 + col);
            if (ctl + 2 < 8) LDB(Ba, ena, ctl + 2);
            COMP(Bb, enb, cbase + (ctl + 1) * 16 + col);
        }
        __syncthreads();
    }

    // reduce across 16 cols per query row (codes ascend with col: lex-min ok)
#pragma unroll
    for (int t = 0; t < 4; ++t) {
        float a1 = d1[t], a2 = d2[t];
        int ai = i1[t];
#pragma unroll
        for (int off = 1; off < 16; off <<= 1) {
            float o1 = __shfl_xor(a1, off, 64);
            float o2 = __shfl_xor(a2, off, 64);
            int   oi = __shfl_xor(ai, off, 64);
            if (o1 < a1 || (o1 == a1 && oi < ai)) {
                float loser = a1; a2 = fminf(fminf(a2, o2), loser); a1 = o1; ai = oi;
            } else {
                a2 = fminf(fminf(a2, o2), o1);
            }
        }
        d1[t] = a1; d2[t] = a2; i1[t] = ai;
    }

    if (tid == 0) nflag = 0;
    if (col == 0) {
#pragma unroll
        for (int reg = 0; reg < 4; ++reg) {
            int m = w * 16 + quad * 4 + reg;
            rd1[m] = d1[reg];
            rd2[m] = d2[reg];
            ri [m] = i1[reg];
        }
    }
    __syncthreads();

    // flag queries with margin < TAU for exact in-block re-solve
    if (tid < QT) {
        if (rd2[tid] - rd1[tid] < TAU) {
            int slot = atomicAdd(&nflag, 1);
            flist[slot] = tid;
        }
    }
    __syncthreads();

    // ---- in-block exact fp32 rescue (avg nflag ~0-1 per block) ----
    for (int f = 0; f < nflag; ++f) {
        const int q = flist[f];
        if (tid < CDIM) xqf[tid] = x[b * (CDIM * HW_SZ) + tid * HW_SZ + hw0 + q];
        __syncthreads();
        float dm = 3.4e38f; int im = 0;
        for (int cd = 0; cd < 2; ++cd) {
            const int k = tid + cd * 512;            // codes ascend with cd
            const float4* er = (const float4*)(emb + k * CDIM);
            const float4* xr = (const float4*)xqf;
            float dot = 0.f;
#pragma unroll 4
            for (int c4 = 0; c4 < 16; ++c4) {
                float4 e = er[c4], xv = xr[c4];
                dot += e.x * xv.x + e.y * xv.y + e.z * xv.z + e.w * xv.w;
            }
            float d = ens[k] - 2.f * dot;            // exact fp32
            if (d < dm) { dm = d; im = k; }
        }
#pragma unroll
        for (int off = 1; off < 64; off <<= 1) {
            float od = __shfl_xor(dm, off, 64);
            int   oi = __shfl_xor(im, off, 64);
            if (od < dm || (od == dm && oi < im)) { dm = od; im = oi; }
        }
        if (lane == 0) { wdd[w] = dm; wii[w] = im; }
        __syncthreads();
        if (tid == 0) {
            float bd = wdd[0]; int bi = wii[0];
#pragma unroll
            for (int ww = 1; ww < 8; ++ww)
                if (wdd[ww] < bd || (wdd[ww] == bd && wii[ww] < bi)) { bd = wdd[ww]; bi = wii[ww]; }
            rd1[q] = bd; ri[q] = bi;                 // final exact result
        }
        __syncthreads();
    }

    // ---- epilogue on FINAL indices: hist atomics (staggered, cheap) + SSE ----
    if (tid < QT) {
        int ai = ri[tid];
        atomicAdd(&hist[ai], 1u);
        float sp = rd1[tid] + xnorm[tid];            // ||q-x||^2 (exact for rescued)
#pragma unroll
        for (int off = 32; off; off >>= 1) sp += __shfl_down(sp, off, 64);
        if (lane == 0) spw[tid >> 6] = sp;
    }
    __syncthreads();
    if (tid == 0) partials[blockIdx.x] = spw[0] + spw[1];

    // ---- output write: two 64-query halves; EXACT fp32 emb gather ----
#pragma unroll
    for (int h = 0; h < 2; ++h) {
        {   // gather: thread = (q = tid>>3, j8 = tid&7) -> 8 dims from emb row
            int q = tid >> 3, j8 = tid & 7;
            int code = ri[h * 64 + q];
            const float4* er = (const float4*)(emb + code * CDIM + j8 * 8);
            float4 e0 = er[0], e1 = er[1];
            float* dst = &tile[q * 73 + j8 * 8];
            *(float4*)&dst[0] = e0;
            *(float4*)&dst[4] = e1;
        }
        __syncthreads();
        {   // transposed coalesced write (stride 73: ~2-way banks, free)
            int c = tid >> 3;
            float* ob = out + b * (CDIM * HW_SZ) + c * HW_SZ + hw0 + h * 64;
#pragma unroll
            for (int p = 0; p < 2; ++p) {
                int q = ((tid & 7) + p * 8) * 4;   // 0..60
                float4 v;
                v.x = tile[(q + 0) * 73 + c];
                v.y = tile[(q + 1) * 73 + c];
                v.z = tile[(q + 2) * 73 + c];
                v.w = tile[(q + 3) * 73 + c];
                *(float4*)&ob[q] = v;
            }
        }
        if (h == 0) __syncthreads();
    }
}

// --------------------------------------------------------------- k_final ----
// 1 block x 256 thr; reads partials (512) + hist (1024). Tiny.
__global__ void k_final(const float* __restrict__ partials,
                        const unsigned int* __restrict__ hist,
                        float* __restrict__ out) {
    int tid = threadIdx.x;   // 256
    float ss = partials[tid] + partials[256 + tid];
    float s = 0.f;
#pragma unroll
    for (int i = 0; i < 4; ++i) {
        float p = (float)hist[i * 256 + tid] * (1.0f / 65536.0f);
        s += p * logf(p + 1e-10f);
    }
    __shared__ float fin[8];
#pragma unroll
    for (int off = 32; off; off >>= 1) {
        ss += __shfl_down(ss, off, 64);
        s  += __shfl_down(s, off, 64);
    }
    if ((tid & 63) == 0) { fin[tid >> 6] = ss; fin[4 + (tid >> 6)] = s; }
    __syncthreads();
    if (tid == 0) {
        float sse = fin[0] + fin[1] + fin[2] + fin[3];
        float ent = fin[4] + fin[5] + fin[6] + fin[7];
        out[OUT_ELEMS]     = 1.25f * sse * (1.0f / (float)OUT_ELEMS);  // loss
        out[OUT_ELEMS + 1] = expf(-ent);                                // perplexity
    }
}

// ---------------------------------------------------------------- launch ----
extern "C" void kernel_launch(void* const* d_in, const int* in_sizes, int n_in,
                              void* d_out, int out_size, void* d_ws, size_t ws_size,
                              hipStream_t stream) {
    const float* x   = (const float*)d_in[0];
    const float* emb = (const float*)d_in[1];
    float* out = (float*)d_out;
    char* ws = (char*)d_ws;
    float*        enorm    = (float*)(ws);
    unsigned int* hist     = (unsigned int*)(ws + 4096);
    float*        partials = (float*)(ws + 8192);
    short*        btab     = (short*)(ws + 12288);

    k_prep  <<<64, 256, 0, stream>>>(emb, enorm, btab, hist);
    k_argmin<<<N_TOTAL / QT, 512, 0, stream>>>(x, emb, btab, enorm, hist, partials, out);
    k_final <<<1, 256, 0, stream>>>(partials, hist, out);
}